// Round 1
// baseline (374.757 us; speedup 1.0000x reference)
//
#include <hip/hip_runtime.h>

// ---------------------------------------------------------------------------
// multitask MLP, MI355X bf16 MFMA implementation
//   B=2048, D=1024, T=4, H=64; 8 x [2048,1024]@[1024,1024] + head
// Plan: task-sort rows -> bf16+transpose weights once per call -> 8 MFMA
// GEMM passes (bf16 acts ping-pong in ws) -> fused head (D->64->1, sigmoid,
// scatter back to original order).
// ---------------------------------------------------------------------------

typedef __attribute__((ext_vector_type(4))) float f32x4;
typedef __attribute__((ext_vector_type(8))) __bf16 bf16x8;
typedef __attribute__((ext_vector_type(4))) unsigned short u16x4;

#define AS1 __attribute__((address_space(1)))
#define AS3 __attribute__((address_space(3)))

static constexpr int B_  = 2048;
static constexpr int D_  = 1024;
static constexpr int T_  = 4;
static constexpr int H_  = 64;
static constexpr int MP_ = 2112;                    // B_ padded by 64 for tile overrun
static constexpr size_t MSZ = (size_t)D_ * D_;      // elems per DxD matrix (1M)

// ws layout (bytes)
static constexpr size_t OFF_PERM = 0;                         // 2048 int
static constexpr size_t OFF_SEG  = 8192;                      // 8 int
static constexpr size_t OFF_W    = 16384;                     // bf16 transposed weights
//   matrices 0..1: ws1 l0,l1 | 2..9: wt1 (t*2+l) | 10..11: ws2 | 12..19: wt2 (t*2+l)
//   then h1t: 4 * [64][1024]
static constexpr size_t H1T_ELEM_OFF = 20 * MSZ;
static constexpr size_t W_ELEMS  = 20 * MSZ + (size_t)T_ * H_ * D_;
static constexpr size_t OFF_XP   = OFF_W + W_ELEMS * 2;
static constexpr size_t ACT_BYTES = (size_t)MP_ * D_ * 2;
static constexpr size_t OFF_A0   = OFF_XP + ACT_BYTES;
static constexpr size_t OFF_A1   = OFF_A0 + ACT_BYTES;
static constexpr size_t WS_NEED  = OFF_A1 + ACT_BYTES;        // ~53 MiB

static __device__ __forceinline__ unsigned short f2bf(float f) {
    union { float f; unsigned int u; } v; v.f = f;
    unsigned int r = v.u + 0x7fffu + ((v.u >> 16) & 1u);      // RNE
    return (unsigned short)(r >> 16);
}

// ---------------------------------------------------------------------------
// 1) per-task segments + permutation (1 block)
// ---------------------------------------------------------------------------
__global__ void perm_kernel(const int* __restrict__ btask,
                            int* __restrict__ perm, int* __restrict__ seg) {
    __shared__ int cnt[T_], cur[T_];
    int tid = threadIdx.x;
    if (tid < T_) cnt[tid] = 0;
    __syncthreads();
    for (int i = tid; i < B_; i += 256) atomicAdd(&cnt[btask[i]], 1);
    __syncthreads();
    if (tid == 0) {
        int s = 0;
        for (int t = 0; t < T_; ++t) {
            seg[t] = s; seg[T_ + t] = cnt[t]; cur[t] = s; s += cnt[t];
        }
    }
    __syncthreads();
    for (int i = tid; i < B_; i += 256) {
        int t = btask[i];
        int p = atomicAdd(&cur[t], 1);
        perm[p] = i;
    }
}

// ---------------------------------------------------------------------------
// 2) fp32 -> bf16 transpose of all weight matrices.  z: matrix id 0..23.
//    DxD matrices: out[n][k] = in[k][n].  h1 (z>=20): in [1024][64] -> out [64][1024].
// ---------------------------------------------------------------------------
__global__ __launch_bounds__(256)
void transpose_cvt(const float* __restrict__ ws1, const float* __restrict__ wt1,
                   const float* __restrict__ ws2, const float* __restrict__ wt2,
                   const float* __restrict__ h1, unsigned short* __restrict__ wb) {
    int z = blockIdx.z;
    const float* src; unsigned short* dst; int C = D_;
    if (z < 2)       { src = ws1 + (size_t)z * MSZ;        dst = wb + (size_t)z * MSZ; }
    else if (z < 10) { src = wt1 + (size_t)(z - 2) * MSZ;  dst = wb + (size_t)z * MSZ; }
    else if (z < 12) { src = ws2 + (size_t)(z - 10) * MSZ; dst = wb + (size_t)z * MSZ; }
    else if (z < 20) { src = wt2 + (size_t)(z - 12) * MSZ; dst = wb + (size_t)z * MSZ; }
    else { src = h1 + (size_t)(z - 20) * (D_ * H_);
           dst = wb + H1T_ELEM_OFF + (size_t)(z - 20) * (D_ * H_); C = H_; }
    int r0 = blockIdx.y * 64, c0 = blockIdx.x * 64;
    if (c0 >= C) return;
    __shared__ float tile[64][65];
    int tid = threadIdx.x;
#pragma unroll
    for (int i = 0; i < 4; ++i) {
        int idx = i * 256 + tid;
        int fr = idx >> 4, fc = (idx & 15) << 2;
        float4 v = *(const float4*)(src + (size_t)(r0 + fr) * C + c0 + fc);
        tile[fr][fc] = v.x; tile[fr][fc + 1] = v.y; tile[fr][fc + 2] = v.z; tile[fr][fc + 3] = v.w;
    }
    __syncthreads();
#pragma unroll
    for (int i = 0; i < 4; ++i) {
        int idx = i * 256 + tid;
        int orow = idx >> 4, ocb = (idx & 15) << 2;
        u16x4 o = { f2bf(tile[ocb][orow]),     f2bf(tile[ocb + 1][orow]),
                    f2bf(tile[ocb + 2][orow]), f2bf(tile[ocb + 3][orow]) };
        *(u16x4*)(dst + (size_t)(c0 + orow) * D_ + r0 + ocb) = o;
    }
}

// ---------------------------------------------------------------------------
// 3) gather x into permuted order, convert to bf16.  1 block = 1 row.
// ---------------------------------------------------------------------------
__global__ void gather_x(const float* __restrict__ x, const int* __restrict__ perm,
                         unsigned short* __restrict__ xp) {
    int pos = blockIdx.x;
    int src = perm[pos];
    int t = threadIdx.x;                       // 256 threads * 4 floats
    float4 v = *((const float4*)(x + (size_t)src * D_) + t);
    u16x4 o = { f2bf(v.x), f2bf(v.y), f2bf(v.z), f2bf(v.w) };
    *((u16x4*)(xp + (size_t)pos * D_) + t) = o;
}

// ---------------------------------------------------------------------------
// 4) GEMM pass: Out[m][n] = act( A[m][:] @ W[:][n] + bias[n] ), bf16 in/out.
//    BM=64 BN=128 BK=64, 4 waves (2x2), wave tile 32x64, mfma 16x16x32 bf16.
//    W given pre-transposed: Wt[n][k].  TASK: blockIdx.y = t*32 + mtile over
//    task segment; partial tiles masked on store (garbage A rows are masked).
// ---------------------------------------------------------------------------
template<bool RELU, bool TASK>
__global__ __launch_bounds__(256)
void gemm_pass(const unsigned short* __restrict__ A, const unsigned short* __restrict__ W,
               const float* __restrict__ bias, unsigned short* __restrict__ Out,
               const int* __restrict__ seg, size_t wstride, size_t bstride) {
    __shared__ unsigned short lA[64 * 64];     //  8 KB
    __shared__ unsigned short lB[128 * 64];    // 16 KB
    int m0, mend, t = 0;
    if (TASK) {
        t = blockIdx.y >> 5;
        int mt = blockIdx.y & 31;
        int s = seg[t], c = seg[4 + t];
        m0 = s + mt * 64; mend = s + c;
        if (m0 >= mend) return;
    } else { m0 = blockIdx.y * 64; mend = B_; }
    const unsigned short* Wt = W + (size_t)t * wstride;
    const float* bs = bias + (size_t)t * bstride;
    const int n0 = blockIdx.x * 128;

    const int tid = threadIdx.x, wid = tid >> 6, lane = tid & 63;
    const int wm = wid >> 1, wn = wid & 1;
    const int l15 = lane & 15, l4 = lane >> 4;
    const int srow = lane >> 3, scolb = (lane & 7) * 16;   // staging: 8 lanes/row, 16B each

    f32x4 acc[2][4] = {};

    for (int k0 = 0; k0 < D_; k0 += 64) {
        if (k0) __syncthreads();               // prev compute done before overwrite
#pragma unroll
        for (int i = 0; i < 2; ++i) {          // A: 8 chunks of 1KB (8 rows x 128B)
            int chunk = wid * 2 + i;
            int row = chunk * 8 + srow;
            const char* src = (const char*)(A + (size_t)(m0 + row) * D_ + k0) + scolb;
            __builtin_amdgcn_global_load_lds((AS1 void*)src, (AS3 void*)(lA + (size_t)chunk * 512), 16, 0, 0);
        }
#pragma unroll
        for (int i = 0; i < 4; ++i) {          // B: 16 chunks
            int chunk = wid * 4 + i;
            int row = chunk * 8 + srow;
            const char* src = (const char*)(Wt + (size_t)(n0 + row) * D_ + k0) + scolb;
            __builtin_amdgcn_global_load_lds((AS1 void*)src, (AS3 void*)(lB + (size_t)chunk * 512), 16, 0, 0);
        }
        __syncthreads();                       // drains vmcnt (global_load_lds) too
#pragma unroll
        for (int kk = 0; kk < 2; ++kk) {
            const int ko = kk * 32 + l4 * 8;
            bf16x8 af[2], bfr[4];
#pragma unroll
            for (int m = 0; m < 2; ++m)
                af[m] = *(const bf16x8*)(lA + (wm * 32 + m * 16 + l15) * 64 + ko);
#pragma unroll
            for (int n = 0; n < 4; ++n)
                bfr[n] = *(const bf16x8*)(lB + (wn * 64 + n * 16 + l15) * 64 + ko);
#pragma unroll
            for (int m = 0; m < 2; ++m)
#pragma unroll
                for (int n = 0; n < 4; ++n)
                    acc[m][n] = __builtin_amdgcn_mfma_f32_16x16x32_bf16(af[m], bfr[n], acc[m][n], 0, 0, 0);
        }
    }
    // epilogue: C/D layout col=lane&15, row=(lane>>4)*4+j  [guide §3, m89-verified]
#pragma unroll
    for (int n = 0; n < 4; ++n) {
        int col = n0 + wn * 64 + n * 16 + l15;
        float bv = bs[col];
#pragma unroll
        for (int m = 0; m < 2; ++m) {
            int rbase = m0 + wm * 32 + m * 16 + l4 * 4;
#pragma unroll
            for (int j = 0; j < 4; ++j) {
                int row = rbase + j;
                if (!TASK || row < mend) {
                    float v = acc[m][n][j] + bv;
                    if (RELU) v = fmaxf(v, 0.f);
                    Out[(size_t)row * D_ + col] = f2bf(v);
                }
            }
        }
    }
}

// ---------------------------------------------------------------------------
// 5) head: r = A @ H1t[t] + h1_b (NO relu), logit = r . h2_W[t] + h2_b[t],
//    out[orig] = sigmoid(logit).  64 rows/block, wave w owns rows w*16..+16.
// ---------------------------------------------------------------------------
__global__ __launch_bounds__(256)
void head_pass(const unsigned short* __restrict__ A, const unsigned short* __restrict__ H1t,
               const float* __restrict__ h1b, const float* __restrict__ h2w,
               const float* __restrict__ h2b, const int* __restrict__ seg,
               const int* __restrict__ perm, float* __restrict__ out) {
    __shared__ unsigned short lA[64 * 64];
    __shared__ unsigned short lB[64 * 64];
    int t = blockIdx.x >> 5, mt = blockIdx.x & 31;
    int s = seg[t], c = seg[4 + t];
    int m0 = s + mt * 64, mend = s + c;
    if (m0 >= mend) return;
    const unsigned short* Ht = H1t + (size_t)t * (H_ * D_);
    const int tid = threadIdx.x, wid = tid >> 6, lane = tid & 63;
    const int l15 = lane & 15, l4 = lane >> 4;
    const int srow = lane >> 3, scolb = (lane & 7) * 16;
    f32x4 acc[4] = {};
    for (int k0 = 0; k0 < D_; k0 += 64) {
        if (k0) __syncthreads();
#pragma unroll
        for (int i = 0; i < 2; ++i) {
            int chunk = wid * 2 + i;
            int row = chunk * 8 + srow;
            const char* sa = (const char*)(A + (size_t)(m0 + row) * D_ + k0) + scolb;
            __builtin_amdgcn_global_load_lds((AS1 void*)sa, (AS3 void*)(lA + (size_t)chunk * 512), 16, 0, 0);
            const char* sb = (const char*)(Ht + (size_t)row * D_ + k0) + scolb;
            __builtin_amdgcn_global_load_lds((AS1 void*)sb, (AS3 void*)(lB + (size_t)chunk * 512), 16, 0, 0);
        }
        __syncthreads();
#pragma unroll
        for (int kk = 0; kk < 2; ++kk) {
            const int ko = kk * 32 + l4 * 8;
            bf16x8 af = *(const bf16x8*)(lA + (wid * 16 + l15) * 64 + ko);
#pragma unroll
            for (int n = 0; n < 4; ++n) {
                bf16x8 bfr = *(const bf16x8*)(lB + (n * 16 + l15) * 64 + ko);
                acc[n] = __builtin_amdgcn_mfma_f32_16x16x32_bf16(af, bfr, acc[n], 0, 0, 0);
            }
        }
    }
    float part[4] = {0.f, 0.f, 0.f, 0.f};
#pragma unroll
    for (int n = 0; n < 4; ++n) {
        int col = n * 16 + l15;
        float b1 = h1b[t * H_ + col];
        float w2 = h2w[t * H_ + col];
#pragma unroll
        for (int j = 0; j < 4; ++j) part[j] += (acc[n][j] + b1) * w2;
    }
#pragma unroll
    for (int msk = 1; msk < 16; msk <<= 1)
#pragma unroll
        for (int j = 0; j < 4; ++j) part[j] += __shfl_xor(part[j], msk);
    if (l15 == 0) {
        float b2 = h2b[t];
#pragma unroll
        for (int j = 0; j < 4; ++j) {
            int row = m0 + wid * 16 + l4 * 4 + j;
            if (row < mend) {
                int orig = perm[row];
                out[orig] = 1.f / (1.f + expf(-(part[j] + b2)));
            }
        }
    }
}

// ---------------------------------------------------------------------------
extern "C" void kernel_launch(void* const* d_in, const int* in_sizes, int n_in,
                              void* d_out, int out_size, void* d_ws, size_t ws_size,
                              hipStream_t stream) {
    (void)in_sizes; (void)n_in; (void)out_size;
    if (ws_size < WS_NEED) return;   // visible clean-fail if scratch too small

    const float* x    = (const float*)d_in[0];
    const int*   bt   = (const int*)d_in[1];
    const float* ws1W = (const float*)d_in[2];
    const float* ws1b = (const float*)d_in[3];
    const float* wt1W = (const float*)d_in[4];
    const float* wt1b = (const float*)d_in[5];
    const float* ws2W = (const float*)d_in[6];
    const float* ws2b = (const float*)d_in[7];
    const float* wt2W = (const float*)d_in[8];
    const float* wt2b = (const float*)d_in[9];
    const float* h1W  = (const float*)d_in[10];
    const float* h1b  = (const float*)d_in[11];
    const float* h2W  = (const float*)d_in[12];
    const float* h2b  = (const float*)d_in[13];

    char* ws = (char*)d_ws;
    int* perm = (int*)(ws + OFF_PERM);
    int* seg  = (int*)(ws + OFF_SEG);
    unsigned short* wb = (unsigned short*)(ws + OFF_W);
    unsigned short* xp = (unsigned short*)(ws + OFF_XP);
    unsigned short* a0 = (unsigned short*)(ws + OFF_A0);
    unsigned short* a1 = (unsigned short*)(ws + OFF_A1);

    perm_kernel<<<1, 256, 0, stream>>>(bt, perm, seg);
    transpose_cvt<<<dim3(16, 16, 24), 256, 0, stream>>>(ws1W, wt1W, ws2W, wt2W, h1W, wb);
    gather_x<<<B_, 256, 0, stream>>>(x, perm, xp);

    dim3 gs(8, 32), gt(8, 128);
    // shared1: lin, then relu->lin  (relu folded into producer epilogue)
    gemm_pass<true,  false><<<gs, 256, 0, stream>>>(xp, wb + 0 * MSZ,  ws1b + 0,  a0, seg, 0, 0);
    gemm_pass<true,  false><<<gs, 256, 0, stream>>>(a0, wb + 1 * MSZ,  ws1b + D_, a1, seg, 0, 0);
    // task1: (relu->lin)x2 ; second layer output feeds shared2 RAW -> no relu
    gemm_pass<true,  true ><<<gt, 256, 0, stream>>>(a1, wb + 2 * MSZ,  wt1b + 0,  a0, seg, 2 * MSZ, 2 * D_);
    gemm_pass<false, true ><<<gt, 256, 0, stream>>>(a0, wb + 3 * MSZ,  wt1b + D_, a1, seg, 2 * MSZ, 2 * D_);
    // shared2
    gemm_pass<true,  false><<<gs, 256, 0, stream>>>(a1, wb + 10 * MSZ, ws2b + 0,  a0, seg, 0, 0);
    gemm_pass<true,  false><<<gs, 256, 0, stream>>>(a0, wb + 11 * MSZ, ws2b + D_, a1, seg, 0, 0);
    // task2 body
    gemm_pass<true,  true ><<<gt, 256, 0, stream>>>(a1, wb + 12 * MSZ, wt2b + 0,  a0, seg, 2 * MSZ, 2 * D_);
    gemm_pass<true,  true ><<<gt, 256, 0, stream>>>(a0, wb + 13 * MSZ, wt2b + D_, a1, seg, 2 * MSZ, 2 * D_);
    // head: D->64 (+bias, no relu), dot h2, sigmoid, scatter
    head_pass<<<dim3(128), 256, 0, stream>>>(a1, wb + H1T_ELEM_OFF, h1b, h2W, h2b, seg, perm, (float*)d_out);
}

// Round 3
// 355.659 us; speedup vs baseline: 1.0537x; 1.0537x over previous
//
#include <hip/hip_runtime.h>

// ---------------------------------------------------------------------------
// multitask MLP, MI355X bf16 MFMA implementation — round 2 (resubmit; r2 bench
// was lost to a GPU-acquisition timeout, no data)
//   B=2048, D=1024, T=4, H=64; 8 x [2048,1024]@[1024,1024] + head
// r1 -> r2: K-loop software pipeline (3 LDS buffers, 2-deep prefetch,
// counted vmcnt(6), raw s_barrier — 1 barrier/k-step, no vmcnt(0) drain).
// ---------------------------------------------------------------------------

typedef __attribute__((ext_vector_type(4))) float f32x4;
typedef __attribute__((ext_vector_type(8))) __bf16 bf16x8;
typedef __attribute__((ext_vector_type(4))) unsigned short u16x4;

#define AS1 __attribute__((address_space(1)))
#define AS3 __attribute__((address_space(3)))

static constexpr int B_  = 2048;
static constexpr int D_  = 1024;
static constexpr int T_  = 4;
static constexpr int H_  = 64;
static constexpr int MP_ = 2112;                    // B_ padded by 64 for tile overrun
static constexpr size_t MSZ = (size_t)D_ * D_;      // elems per DxD matrix (1M)

// ws layout (bytes)
static constexpr size_t OFF_PERM = 0;                         // 2048 int
static constexpr size_t OFF_SEG  = 8192;                      // 8 int
static constexpr size_t OFF_W    = 16384;                     // bf16 transposed weights
//   matrices 0..1: ws1 l0,l1 | 2..9: wt1 (t*2+l) | 10..11: ws2 | 12..19: wt2 (t*2+l)
//   then h1t: 4 * [64][1024]
static constexpr size_t H1T_ELEM_OFF = 20 * MSZ;
static constexpr size_t W_ELEMS  = 20 * MSZ + (size_t)T_ * H_ * D_;
static constexpr size_t OFF_XP   = OFF_W + W_ELEMS * 2;
static constexpr size_t ACT_BYTES = (size_t)MP_ * D_ * 2;
static constexpr size_t OFF_A0   = OFF_XP + ACT_BYTES;
static constexpr size_t OFF_A1   = OFF_A0 + ACT_BYTES;
static constexpr size_t WS_NEED  = OFF_A1 + ACT_BYTES;        // ~53 MiB

static __device__ __forceinline__ unsigned short f2bf(float f) {
    union { float f; unsigned int u; } v; v.f = f;
    unsigned int r = v.u + 0x7fffu + ((v.u >> 16) & 1u);      // RNE
    return (unsigned short)(r >> 16);
}

// ---------------------------------------------------------------------------
// 1) per-task segments + permutation (1 block)
// ---------------------------------------------------------------------------
__global__ void perm_kernel(const int* __restrict__ btask,
                            int* __restrict__ perm, int* __restrict__ seg) {
    __shared__ int cnt[T_], cur[T_];
    int tid = threadIdx.x;
    if (tid < T_) cnt[tid] = 0;
    __syncthreads();
    for (int i = tid; i < B_; i += 256) atomicAdd(&cnt[btask[i]], 1);
    __syncthreads();
    if (tid == 0) {
        int s = 0;
        for (int t = 0; t < T_; ++t) {
            seg[t] = s; seg[T_ + t] = cnt[t]; cur[t] = s; s += cnt[t];
        }
    }
    __syncthreads();
    for (int i = tid; i < B_; i += 256) {
        int t = btask[i];
        int p = atomicAdd(&cur[t], 1);
        perm[p] = i;
    }
}

// ---------------------------------------------------------------------------
// 2) fp32 -> bf16 transpose of all weight matrices.  z: matrix id 0..23.
// ---------------------------------------------------------------------------
__global__ __launch_bounds__(256)
void transpose_cvt(const float* __restrict__ ws1, const float* __restrict__ wt1,
                   const float* __restrict__ ws2, const float* __restrict__ wt2,
                   const float* __restrict__ h1, unsigned short* __restrict__ wb) {
    int z = blockIdx.z;
    const float* src; unsigned short* dst; int C = D_;
    if (z < 2)       { src = ws1 + (size_t)z * MSZ;        dst = wb + (size_t)z * MSZ; }
    else if (z < 10) { src = wt1 + (size_t)(z - 2) * MSZ;  dst = wb + (size_t)z * MSZ; }
    else if (z < 12) { src = ws2 + (size_t)(z - 10) * MSZ; dst = wb + (size_t)z * MSZ; }
    else if (z < 20) { src = wt2 + (size_t)(z - 12) * MSZ; dst = wb + (size_t)z * MSZ; }
    else { src = h1 + (size_t)(z - 20) * (D_ * H_);
           dst = wb + H1T_ELEM_OFF + (size_t)(z - 20) * (D_ * H_); C = H_; }
    int r0 = blockIdx.y * 64, c0 = blockIdx.x * 64;
    if (c0 >= C) return;
    __shared__ float tile[64][65];
    int tid = threadIdx.x;
#pragma unroll
    for (int i = 0; i < 4; ++i) {
        int idx = i * 256 + tid;
        int fr = idx >> 4, fc = (idx & 15) << 2;
        float4 v = *(const float4*)(src + (size_t)(r0 + fr) * C + c0 + fc);
        tile[fr][fc] = v.x; tile[fr][fc + 1] = v.y; tile[fr][fc + 2] = v.z; tile[fr][fc + 3] = v.w;
    }
    __syncthreads();
#pragma unroll
    for (int i = 0; i < 4; ++i) {
        int idx = i * 256 + tid;
        int orow = idx >> 4, ocb = (idx & 15) << 2;
        u16x4 o = { f2bf(tile[ocb][orow]),     f2bf(tile[ocb + 1][orow]),
                    f2bf(tile[ocb + 2][orow]), f2bf(tile[ocb + 3][orow]) };
        *(u16x4*)(dst + (size_t)(c0 + orow) * D_ + r0 + ocb) = o;
    }
}

// ---------------------------------------------------------------------------
// 3) gather x into permuted order, convert to bf16.  1 block = 1 row.
// ---------------------------------------------------------------------------
__global__ void gather_x(const float* __restrict__ x, const int* __restrict__ perm,
                         unsigned short* __restrict__ xp) {
    int pos = blockIdx.x;
    int src = perm[pos];
    int t = threadIdx.x;                       // 256 threads * 4 floats
    float4 v = *((const float4*)(x + (size_t)src * D_) + t);
    u16x4 o = { f2bf(v.x), f2bf(v.y), f2bf(v.z), f2bf(v.w) };
    *((u16x4*)(xp + (size_t)pos * D_) + t) = o;
}

// ---------------------------------------------------------------------------
// 4) GEMM pass, software-pipelined.
//    BM=64 BN=128 BK=64, 4 waves (2x2), wave tile 32x64, mfma 16x16x32 bf16.
//    3 LDS buffers, stage(t+2) in iter t, steady-state s_waitcnt vmcnt(6),
//    ONE raw s_barrier per k-step:
//      iter t: vmcnt(6) -> barrier -> stage(t+2) -> ds_read(t) -> MFMA
//    (stage(t+2) overwrites buf[(t-1)%3]; iter-t barrier separates it from
//     iter t-1's ds_reads.  vmcnt(6) leaves stage(t+1) in flight, forces
//     stage(t) landed; barrier makes that true for ALL waves' chunks.)
// ---------------------------------------------------------------------------
template<bool RELU, bool TASK>
__global__ __launch_bounds__(256)
void gemm_pass(const unsigned short* __restrict__ A, const unsigned short* __restrict__ W,
               const float* __restrict__ bias, unsigned short* __restrict__ Out,
               const int* __restrict__ seg, size_t wstride, size_t bstride) {
    __shared__ unsigned short lA[3][64 * 64];      // 3 x  8 KB
    __shared__ unsigned short lB[3][128 * 64];     // 3 x 16 KB  (72 KB total)
    int m0, mend, t = 0;
    if (TASK) {
        t = blockIdx.y >> 5;
        int mt = blockIdx.y & 31;
        int s = seg[t], c = seg[4 + t];
        m0 = s + mt * 64; mend = s + c;
        if (m0 >= mend) return;
    } else { m0 = blockIdx.y * 64; mend = B_; }
    const unsigned short* Wt = W + (size_t)t * wstride;
    const float* bs = bias + (size_t)t * bstride;
    const int n0 = blockIdx.x * 128;

    const int tid = threadIdx.x, wid = tid >> 6, lane = tid & 63;
    const int wm = wid >> 1, wn = wid & 1;
    const int l15 = lane & 15, l4 = lane >> 4;
    const int srow = lane >> 3, scolb = (lane & 7) * 16;   // staging: 8 lanes/row, 16B each

    f32x4 acc[2][4] = {};

    auto stage = [&](int kt, int buf) {
        const int k0 = kt * 64;
#pragma unroll
        for (int i = 0; i < 2; ++i) {              // A: 8 chunks of 1KB
            int chunk = wid * 2 + i;
            int row = chunk * 8 + srow;
            const char* src = (const char*)(A + (size_t)(m0 + row) * D_ + k0) + scolb;
            __builtin_amdgcn_global_load_lds((AS1 void*)src,
                (AS3 void*)(&lA[buf][0] + (size_t)chunk * 512), 16, 0, 0);
        }
#pragma unroll
        for (int i = 0; i < 4; ++i) {              // B: 16 chunks
            int chunk = wid * 4 + i;
            int row = chunk * 8 + srow;
            const char* src = (const char*)(Wt + (size_t)(n0 + row) * D_ + k0) + scolb;
            __builtin_amdgcn_global_load_lds((AS1 void*)src,
                (AS3 void*)(&lB[buf][0] + (size_t)chunk * 512), 16, 0, 0);
        }
    };

    auto compute = [&](int buf) {
        const unsigned short* bA = &lA[buf][0];
        const unsigned short* bB = &lB[buf][0];
#pragma unroll
        for (int kk = 0; kk < 2; ++kk) {
            const int ko = kk * 32 + l4 * 8;
            bf16x8 af[2], bfr[4];
#pragma unroll
            for (int m = 0; m < 2; ++m)
                af[m] = *(const bf16x8*)(bA + (wm * 32 + m * 16 + l15) * 64 + ko);
#pragma unroll
            for (int n = 0; n < 4; ++n)
                bfr[n] = *(const bf16x8*)(bB + (wn * 64 + n * 16 + l15) * 64 + ko);
#pragma unroll
            for (int m = 0; m < 2; ++m)
#pragma unroll
                for (int n = 0; n < 4; ++n)
                    acc[m][n] = __builtin_amdgcn_mfma_f32_16x16x32_bf16(af[m], bfr[n], acc[m][n], 0, 0, 0);
        }
    };

    stage(0, 0);
    stage(1, 1);
    int bc = 0, bn2 = 2;
#pragma unroll 1
    for (int kt = 0; kt < 14; ++kt) {              // 16 k-steps total, 2 peeled
        asm volatile("s_waitcnt vmcnt(6)" ::: "memory");
        __builtin_amdgcn_s_barrier();
        stage(kt + 2, bn2);
        compute(bc);
        bc  = (bc  == 2) ? 0 : bc  + 1;
        bn2 = (bn2 == 2) ? 0 : bn2 + 1;
    }
    asm volatile("s_waitcnt vmcnt(6)" ::: "memory");
    __builtin_amdgcn_s_barrier();
    compute(bc);
    bc = (bc == 2) ? 0 : bc + 1;
    asm volatile("s_waitcnt vmcnt(0)" ::: "memory");
    __builtin_amdgcn_s_barrier();
    compute(bc);

    // epilogue: C/D layout col=lane&15, row=(lane>>4)*4+j  [guide §3, m89-verified]
#pragma unroll
    for (int n = 0; n < 4; ++n) {
        int col = n0 + wn * 64 + n * 16 + l15;
        float bv = bs[col];
#pragma unroll
        for (int m = 0; m < 2; ++m) {
            int rbase = m0 + wm * 32 + m * 16 + l4 * 4;
#pragma unroll
            for (int j = 0; j < 4; ++j) {
                int row = rbase + j;
                if (!TASK || row < mend) {
                    float v = acc[m][n][j] + bv;
                    if (RELU) v = fmaxf(v, 0.f);
                    Out[(size_t)row * D_ + col] = f2bf(v);
                }
            }
        }
    }
}

// ---------------------------------------------------------------------------
// 5) head, same pipeline (vmcnt(4) steady): r = A @ H1t[t] + h1_b (no relu),
//    logit = r . h2_W[t] + h2_b[t], out[orig] = sigmoid(logit).
// ---------------------------------------------------------------------------
__global__ __launch_bounds__(256)
void head_pass(const unsigned short* __restrict__ A, const unsigned short* __restrict__ H1t,
               const float* __restrict__ h1b, const float* __restrict__ h2w,
               const float* __restrict__ h2b, const int* __restrict__ seg,
               const int* __restrict__ perm, float* __restrict__ out) {
    __shared__ unsigned short lA[3][64 * 64];
    __shared__ unsigned short lB[3][64 * 64];      // 48 KB total
    int t = blockIdx.x >> 5, mt = blockIdx.x & 31;
    int s = seg[t], c = seg[4 + t];
    int m0 = s + mt * 64, mend = s + c;
    if (m0 >= mend) return;
    const unsigned short* Ht = H1t + (size_t)t * (H_ * D_);
    const int tid = threadIdx.x, wid = tid >> 6, lane = tid & 63;
    const int l15 = lane & 15, l4 = lane >> 4;
    const int srow = lane >> 3, scolb = (lane & 7) * 16;
    f32x4 acc[4] = {};

    auto stage = [&](int kt, int buf) {
        const int k0 = kt * 64;
#pragma unroll
        for (int i = 0; i < 2; ++i) {
            int chunk = wid * 2 + i;
            int row = chunk * 8 + srow;
            const char* sa = (const char*)(A + (size_t)(m0 + row) * D_ + k0) + scolb;
            __builtin_amdgcn_global_load_lds((AS1 void*)sa,
                (AS3 void*)(&lA[buf][0] + (size_t)chunk * 512), 16, 0, 0);
            const char* sb = (const char*)(Ht + (size_t)row * D_ + k0) + scolb;
            __builtin_amdgcn_global_load_lds((AS1 void*)sb,
                (AS3 void*)(&lB[buf][0] + (size_t)chunk * 512), 16, 0, 0);
        }
    };
    auto compute = [&](int buf) {
#pragma unroll
        for (int kk = 0; kk < 2; ++kk) {
            const int ko = kk * 32 + l4 * 8;
            bf16x8 af = *(const bf16x8*)(&lA[buf][0] + (wid * 16 + l15) * 64 + ko);
#pragma unroll
            for (int n = 0; n < 4; ++n) {
                bf16x8 bfr = *(const bf16x8*)(&lB[buf][0] + (n * 16 + l15) * 64 + ko);
                acc[n] = __builtin_amdgcn_mfma_f32_16x16x32_bf16(af, bfr, acc[n], 0, 0, 0);
            }
        }
    };

    stage(0, 0);
    stage(1, 1);
    int bc = 0, bn2 = 2;
#pragma unroll 1
    for (int kt = 0; kt < 14; ++kt) {
        asm volatile("s_waitcnt vmcnt(4)" ::: "memory");
        __builtin_amdgcn_s_barrier();
        stage(kt + 2, bn2);
        compute(bc);
        bc  = (bc  == 2) ? 0 : bc  + 1;
        bn2 = (bn2 == 2) ? 0 : bn2 + 1;
    }
    asm volatile("s_waitcnt vmcnt(4)" ::: "memory");
    __builtin_amdgcn_s_barrier();
    compute(bc);
    bc = (bc == 2) ? 0 : bc + 1;
    asm volatile("s_waitcnt vmcnt(0)" ::: "memory");
    __builtin_amdgcn_s_barrier();
    compute(bc);

    float part[4] = {0.f, 0.f, 0.f, 0.f};
#pragma unroll
    for (int n = 0; n < 4; ++n) {
        int col = n * 16 + l15;
        float b1 = h1b[t * H_ + col];
        float w2 = h2w[t * H_ + col];
#pragma unroll
        for (int j = 0; j < 4; ++j) part[j] += (acc[n][j] + b1) * w2;
    }
#pragma unroll
    for (int msk = 1; msk < 16; msk <<= 1)
#pragma unroll
        for (int j = 0; j < 4; ++j) part[j] += __shfl_xor(part[j], msk);
    if (l15 == 0) {
        float b2 = h2b[t];
#pragma unroll
        for (int j = 0; j < 4; ++j) {
            int row = m0 + wid * 16 + l4 * 4 + j;
            if (row < mend) {
                int orig = perm[row];
                out[orig] = 1.f / (1.f + expf(-(part[j] + b2)));
            }
        }
    }
}

// ---------------------------------------------------------------------------
extern "C" void kernel_launch(void* const* d_in, const int* in_sizes, int n_in,
                              void* d_out, int out_size, void* d_ws, size_t ws_size,
                              hipStream_t stream) {
    (void)in_sizes; (void)n_in; (void)out_size;
    if (ws_size < WS_NEED) return;   // visible clean-fail if scratch too small

    const float* x    = (const float*)d_in[0];
    const int*   bt   = (const int*)d_in[1];
    const float* ws1W = (const float*)d_in[2];
    const float* ws1b = (const float*)d_in[3];
    const float* wt1W = (const float*)d_in[4];
    const float* wt1b = (const float*)d_in[5];
    const float* ws2W = (const float*)d_in[6];
    const float* ws2b = (const float*)d_in[7];
    const float* wt2W = (const float*)d_in[8];
    const float* wt2b = (const float*)d_in[9];
    const float* h1W  = (const float*)d_in[10];
    const float* h1b  = (const float*)d_in[11];
    const float* h2W  = (const float*)d_in[12];
    const float* h2b  = (const float*)d_in[13];

    char* ws = (char*)d_ws;
    int* perm = (int*)(ws + OFF_PERM);
    int* seg  = (int*)(ws + OFF_SEG);
    unsigned short* wb = (unsigned short*)(ws + OFF_W);
    unsigned short* xp = (unsigned short*)(ws + OFF_XP);
    unsigned short* a0 = (unsigned short*)(ws + OFF_A0);
    unsigned short* a1 = (unsigned short*)(ws + OFF_A1);

    perm_kernel<<<1, 256, 0, stream>>>(bt, perm, seg);
    transpose_cvt<<<dim3(16, 16, 24), 256, 0, stream>>>(ws1W, wt1W, ws2W, wt2W, h1W, wb);
    gather_x<<<B_, 256, 0, stream>>>(x, perm, xp);

    dim3 gs(8, 32), gt(8, 128);
    // shared1: lin, then relu->lin  (relu folded into producer epilogue)
    gemm_pass<true,  false><<<gs, 256, 0, stream>>>(xp, wb + 0 * MSZ,  ws1b + 0,  a0, seg, 0, 0);
    gemm_pass<true,  false><<<gs, 256, 0, stream>>>(a0, wb + 1 * MSZ,  ws1b + D_, a1, seg, 0, 0);
    // task1: (relu->lin)x2 ; second layer output feeds shared2 RAW -> no relu
    gemm_pass<true,  true ><<<gt, 256, 0, stream>>>(a1, wb + 2 * MSZ,  wt1b + 0,  a0, seg, 2 * MSZ, 2 * D_);
    gemm_pass<false, true ><<<gt, 256, 0, stream>>>(a0, wb + 3 * MSZ,  wt1b + D_, a1, seg, 2 * MSZ, 2 * D_);
    // shared2
    gemm_pass<true,  false><<<gs, 256, 0, stream>>>(a1, wb + 10 * MSZ, ws2b + 0,  a0, seg, 0, 0);
    gemm_pass<true,  false><<<gs, 256, 0, stream>>>(a0, wb + 11 * MSZ, ws2b + D_, a1, seg, 0, 0);
    // task2 body
    gemm_pass<true,  true ><<<gt, 256, 0, stream>>>(a1, wb + 12 * MSZ, wt2b + 0,  a0, seg, 2 * MSZ, 2 * D_);
    gemm_pass<true,  true ><<<gt, 256, 0, stream>>>(a0, wb + 13 * MSZ, wt2b + D_, a1, seg, 2 * MSZ, 2 * D_);
    // head: D->64 (+bias, no relu), dot h2, sigmoid, scatter
    head_pass<<<dim3(128), 256, 0, stream>>>(a1, wb + H1T_ELEM_OFF, h1b, h2W, h2b, seg, perm, (float*)d_out);
}

// Round 5
// 271.192 us; speedup vs baseline: 1.3819x; 1.3115x over previous
//
#include <hip/hip_runtime.h>

// ---------------------------------------------------------------------------
// multitask MLP, MI355X bf16 MFMA — round 4 (resubmit; r4 bench lost to GPU
// acquisition timeout, no data)
//   B=2048, D=1024, T=4, H=64; 8 x [2048,1024]@[1024,1024] + head
// r2 -> r4: (1) tile 64x64, 2 blocks/CU (2 waves/SIMD) for latency hiding;
//           (2) XOR slot-swizzle on LDS (pre-swizzled global source +
//               swizzled ds_read; LDS dest stays linear for global_load_lds)
//               -> 16-way bank conflict eliminated.
// Pipeline kept: 3 LDS buffers, 2-deep prefetch, counted vmcnt(4), 1 barrier.
// ---------------------------------------------------------------------------

typedef __attribute__((ext_vector_type(4))) float f32x4;
typedef __attribute__((ext_vector_type(8))) __bf16 bf16x8;
typedef __attribute__((ext_vector_type(4))) unsigned short u16x4;

#define AS1 __attribute__((address_space(1)))
#define AS3 __attribute__((address_space(3)))

static constexpr int B_  = 2048;
static constexpr int D_  = 1024;
static constexpr int T_  = 4;
static constexpr int H_  = 64;
static constexpr int MP_ = 2112;                    // B_ padded by 64 for tile overrun
static constexpr size_t MSZ = (size_t)D_ * D_;      // elems per DxD matrix (1M)

// ws layout (bytes)
static constexpr size_t OFF_PERM = 0;                         // 2048 int
static constexpr size_t OFF_SEG  = 8192;                      // 8 int
static constexpr size_t OFF_W    = 16384;                     // bf16 transposed weights
//   matrices 0..1: ws1 l0,l1 | 2..9: wt1 (t*2+l) | 10..11: ws2 | 12..19: wt2 (t*2+l)
//   then h1t: 4 * [64][1024]
static constexpr size_t H1T_ELEM_OFF = 20 * MSZ;
static constexpr size_t W_ELEMS  = 20 * MSZ + (size_t)T_ * H_ * D_;
static constexpr size_t OFF_XP   = OFF_W + W_ELEMS * 2;
static constexpr size_t ACT_BYTES = (size_t)MP_ * D_ * 2;
static constexpr size_t OFF_A0   = OFF_XP + ACT_BYTES;
static constexpr size_t OFF_A1   = OFF_A0 + ACT_BYTES;
static constexpr size_t WS_NEED  = OFF_A1 + ACT_BYTES;        // ~53 MiB

static __device__ __forceinline__ unsigned short f2bf(float f) {
    union { float f; unsigned int u; } v; v.f = f;
    unsigned int r = v.u + 0x7fffu + ((v.u >> 16) & 1u);      // RNE
    return (unsigned short)(r >> 16);
}

// ---------------------------------------------------------------------------
// 1) per-task segments + permutation (1 block)
// ---------------------------------------------------------------------------
__global__ void perm_kernel(const int* __restrict__ btask,
                            int* __restrict__ perm, int* __restrict__ seg) {
    __shared__ int cnt[T_], cur[T_];
    int tid = threadIdx.x;
    if (tid < T_) cnt[tid] = 0;
    __syncthreads();
    for (int i = tid; i < B_; i += 256) atomicAdd(&cnt[btask[i]], 1);
    __syncthreads();
    if (tid == 0) {
        int s = 0;
        for (int t = 0; t < T_; ++t) {
            seg[t] = s; seg[T_ + t] = cnt[t]; cur[t] = s; s += cnt[t];
        }
    }
    __syncthreads();
    for (int i = tid; i < B_; i += 256) {
        int t = btask[i];
        int p = atomicAdd(&cur[t], 1);
        perm[p] = i;
    }
}

// ---------------------------------------------------------------------------
// 2) fp32 -> bf16 transpose of all weight matrices.  z: matrix id 0..23.
// ---------------------------------------------------------------------------
__global__ __launch_bounds__(256)
void transpose_cvt(const float* __restrict__ ws1, const float* __restrict__ wt1,
                   const float* __restrict__ ws2, const float* __restrict__ wt2,
                   const float* __restrict__ h1, unsigned short* __restrict__ wb) {
    int z = blockIdx.z;
    const float* src; unsigned short* dst; int C = D_;
    if (z < 2)       { src = ws1 + (size_t)z * MSZ;        dst = wb + (size_t)z * MSZ; }
    else if (z < 10) { src = wt1 + (size_t)(z - 2) * MSZ;  dst = wb + (size_t)z * MSZ; }
    else if (z < 12) { src = ws2 + (size_t)(z - 10) * MSZ; dst = wb + (size_t)z * MSZ; }
    else if (z < 20) { src = wt2 + (size_t)(z - 12) * MSZ; dst = wb + (size_t)z * MSZ; }
    else { src = h1 + (size_t)(z - 20) * (D_ * H_);
           dst = wb + H1T_ELEM_OFF + (size_t)(z - 20) * (D_ * H_); C = H_; }
    int r0 = blockIdx.y * 64, c0 = blockIdx.x * 64;
    if (c0 >= C) return;
    __shared__ float tile[64][65];
    int tid = threadIdx.x;
#pragma unroll
    for (int i = 0; i < 4; ++i) {
        int idx = i * 256 + tid;
        int fr = idx >> 4, fc = (idx & 15) << 2;
        float4 v = *(const float4*)(src + (size_t)(r0 + fr) * C + c0 + fc);
        tile[fr][fc] = v.x; tile[fr][fc + 1] = v.y; tile[fr][fc + 2] = v.z; tile[fr][fc + 3] = v.w;
    }
    __syncthreads();
#pragma unroll
    for (int i = 0; i < 4; ++i) {
        int idx = i * 256 + tid;
        int orow = idx >> 4, ocb = (idx & 15) << 2;
        u16x4 o = { f2bf(tile[ocb][orow]),     f2bf(tile[ocb + 1][orow]),
                    f2bf(tile[ocb + 2][orow]), f2bf(tile[ocb + 3][orow]) };
        *(u16x4*)(dst + (size_t)(c0 + orow) * D_ + r0 + ocb) = o;
    }
}

// ---------------------------------------------------------------------------
// 3) gather x into permuted order, convert to bf16.  1 block = 1 row.
// ---------------------------------------------------------------------------
__global__ void gather_x(const float* __restrict__ x, const int* __restrict__ perm,
                         unsigned short* __restrict__ xp) {
    int pos = blockIdx.x;
    int src = perm[pos];
    int t = threadIdx.x;                       // 256 threads * 4 floats
    float4 v = *((const float4*)(x + (size_t)src * D_) + t);
    u16x4 o = { f2bf(v.x), f2bf(v.y), f2bf(v.z), f2bf(v.w) };
    *((u16x4*)(xp + (size_t)pos * D_) + t) = o;
}

// ---------------------------------------------------------------------------
// 4) GEMM pass, software-pipelined, swizzled.
//    BM=64 BN=64 BK=64, 4 waves (2x2), wave tile 32x32, mfma 16x16x32 bf16.
//    LDS rows are 128B (8 x 16B slots); logical (row, slot) lives at LDS slot
//    (slot ^ (row&7)).  global_load_lds writes linearly (lane L -> slot L&7 of
//    row chunk*8+L/8), so lane L's GLOBAL source is pre-swizzled to slot
//    (L&7)^(L/8 & 7).  ds_read applies the same XOR -> conflict-free (2-way).
//    Pipeline per iter t: vmcnt(4) -> barrier -> stage(t+2) -> compute(t).
// ---------------------------------------------------------------------------
template<bool RELU, bool TASK>
__global__ __launch_bounds__(256)
void gemm_pass(const unsigned short* __restrict__ A, const unsigned short* __restrict__ W,
               const float* __restrict__ bias, unsigned short* __restrict__ Out,
               const int* __restrict__ seg, size_t wstride, size_t bstride) {
    __shared__ unsigned short lA[3][64 * 64];      // 3 x 8 KB
    __shared__ unsigned short lB[3][64 * 64];      // 3 x 8 KB   (48 KB total)
    int m0, mend, t = 0;
    if (TASK) {
        t = blockIdx.y >> 5;
        int mt = blockIdx.y & 31;
        int s = seg[t], c = seg[4 + t];
        m0 = s + mt * 64; mend = s + c;
        if (m0 >= mend) return;
    } else { m0 = blockIdx.y * 64; mend = B_; }
    const unsigned short* Wt = W + (size_t)t * wstride;
    const float* bs = bias + (size_t)t * bstride;
    const int n0 = blockIdx.x * 64;

    const int tid = threadIdx.x, wid = tid >> 6, lane = tid & 63;
    const int wm = wid >> 1, wn = wid & 1;
    const int l15 = lane & 15, l4 = lane >> 4;
    const int srow = lane >> 3;                         // 0..7 within chunk
    const int sslot = ((lane & 7) ^ srow) * 16;         // pre-swizzled source slot (bytes)

    f32x4 acc[2][2] = {};

    auto stage = [&](int kt, int buf) {
        const int k0 = kt * 64;
#pragma unroll
        for (int i = 0; i < 2; ++i) {                   // 2 A-chunks + 2 B-chunks / wave
            int chunk = wid * 2 + i;
            int row = chunk * 8 + srow;
            const char* sa = (const char*)(A + (size_t)(m0 + row) * D_ + k0) + sslot;
            __builtin_amdgcn_global_load_lds((AS1 void*)sa,
                (AS3 void*)(&lA[buf][0] + (size_t)chunk * 512), 16, 0, 0);
            const char* sb = (const char*)(Wt + (size_t)(n0 + row) * D_ + k0) + sslot;
            __builtin_amdgcn_global_load_lds((AS1 void*)sb,
                (AS3 void*)(&lB[buf][0] + (size_t)chunk * 512), 16, 0, 0);
        }
    };

    auto compute = [&](int buf) {
        const unsigned short* bA = &lA[buf][0];
        const unsigned short* bB = &lB[buf][0];
#pragma unroll
        for (int kk = 0; kk < 2; ++kk) {
            const int swz = (((kk * 4) + l4) ^ (l15 & 7)) * 8;   // swizzled k-offset (elems)
            bf16x8 af[2], bfr[2];
#pragma unroll
            for (int m = 0; m < 2; ++m)
                af[m] = *(const bf16x8*)(bA + (wm * 32 + m * 16 + l15) * 64 + swz);
#pragma unroll
            for (int n = 0; n < 2; ++n)
                bfr[n] = *(const bf16x8*)(bB + (wn * 32 + n * 16 + l15) * 64 + swz);
#pragma unroll
            for (int m = 0; m < 2; ++m)
#pragma unroll
                for (int n = 0; n < 2; ++n)
                    acc[m][n] = __builtin_amdgcn_mfma_f32_16x16x32_bf16(af[m], bfr[n], acc[m][n], 0, 0, 0);
        }
    };

    stage(0, 0);
    stage(1, 1);
    int bc = 0, bn2 = 2;
#pragma unroll 1
    for (int kt = 0; kt < 14; ++kt) {              // 16 k-steps total, 2 peeled
        asm volatile("s_waitcnt vmcnt(4)" ::: "memory");
        __builtin_amdgcn_s_barrier();
        stage(kt + 2, bn2);
        compute(bc);
        bc  = (bc  == 2) ? 0 : bc  + 1;
        bn2 = (bn2 == 2) ? 0 : bn2 + 1;
    }
    asm volatile("s_waitcnt vmcnt(4)" ::: "memory");
    __builtin_amdgcn_s_barrier();
    compute(bc);
    bc = (bc == 2) ? 0 : bc + 1;
    asm volatile("s_waitcnt vmcnt(0)" ::: "memory");
    __builtin_amdgcn_s_barrier();
    compute(bc);

    // epilogue: C/D layout col=lane&15, row=(lane>>4)*4+j  [guide §3, m89-verified]
#pragma unroll
    for (int n = 0; n < 2; ++n) {
        int col = n0 + wn * 32 + n * 16 + l15;
        float bv = bs[col];
#pragma unroll
        for (int m = 0; m < 2; ++m) {
            int rbase = m0 + wm * 32 + m * 16 + l4 * 4;
#pragma unroll
            for (int j = 0; j < 4; ++j) {
                int row = rbase + j;
                if (!TASK || row < mend) {
                    float v = acc[m][n][j] + bv;
                    if (RELU) v = fmaxf(v, 0.f);
                    Out[(size_t)row * D_ + col] = f2bf(v);
                }
            }
        }
    }
}

// ---------------------------------------------------------------------------
// 5) head, same pipeline + swizzle (vmcnt(4) steady): r = A @ H1t[t] + h1_b
//    (no relu), logit = r . h2_W[t] + h2_b[t], out[orig] = sigmoid(logit).
// ---------------------------------------------------------------------------
__global__ __launch_bounds__(256)
void head_pass(const unsigned short* __restrict__ A, const unsigned short* __restrict__ H1t,
               const float* __restrict__ h1b, const float* __restrict__ h2w,
               const float* __restrict__ h2b, const int* __restrict__ seg,
               const int* __restrict__ perm, float* __restrict__ out) {
    __shared__ unsigned short lA[3][64 * 64];
    __shared__ unsigned short lB[3][64 * 64];      // 48 KB total
    int t = blockIdx.x >> 5, mt = blockIdx.x & 31;
    int s = seg[t], c = seg[4 + t];
    int m0 = s + mt * 64, mend = s + c;
    if (m0 >= mend) return;
    const unsigned short* Ht = H1t + (size_t)t * (H_ * D_);
    const int tid = threadIdx.x, wid = tid >> 6, lane = tid & 63;
    const int l15 = lane & 15, l4 = lane >> 4;
    const int srow = lane >> 3;
    const int sslot = ((lane & 7) ^ srow) * 16;
    f32x4 acc[4] = {};

    auto stage = [&](int kt, int buf) {
        const int k0 = kt * 64;
#pragma unroll
        for (int i = 0; i < 2; ++i) {
            int chunk = wid * 2 + i;
            int row = chunk * 8 + srow;
            const char* sa = (const char*)(A + (size_t)(m0 + row) * D_ + k0) + sslot;
            __builtin_amdgcn_global_load_lds((AS1 void*)sa,
                (AS3 void*)(&lA[buf][0] + (size_t)chunk * 512), 16, 0, 0);
            const char* sb = (const char*)(Ht + (size_t)row * D_ + k0) + sslot;
            __builtin_amdgcn_global_load_lds((AS1 void*)sb,
                (AS3 void*)(&lB[buf][0] + (size_t)chunk * 512), 16, 0, 0);
        }
    };
    auto compute = [&](int buf) {
#pragma unroll
        for (int kk = 0; kk < 2; ++kk) {
            const int swz = (((kk * 4) + l4) ^ (l15 & 7)) * 8;
            bf16x8 af = *(const bf16x8*)(&lA[buf][0] + (wid * 16 + l15) * 64 + swz);
#pragma unroll
            for (int n = 0; n < 4; ++n) {
                bf16x8 bfr = *(const bf16x8*)(&lB[buf][0] + (n * 16 + l15) * 64 + swz);
                acc[n] = __builtin_amdgcn_mfma_f32_16x16x32_bf16(af, bfr, acc[n], 0, 0, 0);
            }
        }
    };

    stage(0, 0);
    stage(1, 1);
    int bc = 0, bn2 = 2;
#pragma unroll 1
    for (int kt = 0; kt < 14; ++kt) {
        asm volatile("s_waitcnt vmcnt(4)" ::: "memory");
        __builtin_amdgcn_s_barrier();
        stage(kt + 2, bn2);
        compute(bc);
        bc  = (bc  == 2) ? 0 : bc  + 1;
        bn2 = (bn2 == 2) ? 0 : bn2 + 1;
    }
    asm volatile("s_waitcnt vmcnt(4)" ::: "memory");
    __builtin_amdgcn_s_barrier();
    compute(bc);
    bc = (bc == 2) ? 0 : bc + 1;
    asm volatile("s_waitcnt vmcnt(0)" ::: "memory");
    __builtin_amdgcn_s_barrier();
    compute(bc);

    float part[4] = {0.f, 0.f, 0.f, 0.f};
#pragma unroll
    for (int n = 0; n < 4; ++n) {
        int col = n * 16 + l15;
        float b1 = h1b[t * H_ + col];
        float w2 = h2w[t * H_ + col];
#pragma unroll
        for (int j = 0; j < 4; ++j) part[j] += (acc[n][j] + b1) * w2;
    }
#pragma unroll
    for (int msk = 1; msk < 16; msk <<= 1)
#pragma unroll
        for (int j = 0; j < 4; ++j) part[j] += __shfl_xor(part[j], msk);
    if (l15 == 0) {
        float b2 = h2b[t];
#pragma unroll
        for (int j = 0; j < 4; ++j) {
            int row = m0 + wid * 16 + l4 * 4 + j;
            if (row < mend) {
                int orig = perm[row];
                out[orig] = 1.f / (1.f + expf(-(part[j] + b2)));
            }
        }
    }
}

// ---------------------------------------------------------------------------
extern "C" void kernel_launch(void* const* d_in, const int* in_sizes, int n_in,
                              void* d_out, int out_size, void* d_ws, size_t ws_size,
                              hipStream_t stream) {
    (void)in_sizes; (void)n_in; (void)out_size;
    if (ws_size < WS_NEED) return;   // visible clean-fail if scratch too small

    const float* x    = (const float*)d_in[0];
    const int*   bt   = (const int*)d_in[1];
    const float* ws1W = (const float*)d_in[2];
    const float* ws1b = (const float*)d_in[3];
    const float* wt1W = (const float*)d_in[4];
    const float* wt1b = (const float*)d_in[5];
    const float* ws2W = (const float*)d_in[6];
    const float* ws2b = (const float*)d_in[7];
    const float* wt2W = (const float*)d_in[8];
    const float* wt2b = (const float*)d_in[9];
    const float* h1W  = (const float*)d_in[10];
    const float* h1b  = (const float*)d_in[11];
    const float* h2W  = (const float*)d_in[12];
    const float* h2b  = (const float*)d_in[13];

    char* ws = (char*)d_ws;
    int* perm = (int*)(ws + OFF_PERM);
    int* seg  = (int*)(ws + OFF_SEG);
    unsigned short* wb = (unsigned short*)(ws + OFF_W);
    unsigned short* xp = (unsigned short*)(ws + OFF_XP);
    unsigned short* a0 = (unsigned short*)(ws + OFF_A0);
    unsigned short* a1 = (unsigned short*)(ws + OFF_A1);

    perm_kernel<<<1, 256, 0, stream>>>(bt, perm, seg);
    transpose_cvt<<<dim3(16, 16, 24), 256, 0, stream>>>(ws1W, wt1W, ws2W, wt2W, h1W, wb);
    gather_x<<<B_, 256, 0, stream>>>(x, perm, xp);

    dim3 gs(16, 32), gt(16, 128);
    // shared1: lin, then relu->lin  (relu folded into producer epilogue)
    gemm_pass<true,  false><<<gs, 256, 0, stream>>>(xp, wb + 0 * MSZ,  ws1b + 0,  a0, seg, 0, 0);
    gemm_pass<true,  false><<<gs, 256, 0, stream>>>(a0, wb + 1 * MSZ,  ws1b + D_, a1, seg, 0, 0);
    // task1: (relu->lin)x2 ; second layer output feeds shared2 RAW -> no relu
    gemm_pass<true,  true ><<<gt, 256, 0, stream>>>(a1, wb + 2 * MSZ,  wt1b + 0,  a0, seg, 2 * MSZ, 2 * D_);
    gemm_pass<false, true ><<<gt, 256, 0, stream>>>(a0, wb + 3 * MSZ,  wt1b + D_, a1, seg, 2 * MSZ, 2 * D_);
    // shared2
    gemm_pass<true,  false><<<gs, 256, 0, stream>>>(a1, wb + 10 * MSZ, ws2b + 0,  a0, seg, 0, 0);
    gemm_pass<true,  false><<<gs, 256, 0, stream>>>(a0, wb + 11 * MSZ, ws2b + D_, a1, seg, 0, 0);
    // task2 body
    gemm_pass<true,  true ><<<gt, 256, 0, stream>>>(a1, wb + 12 * MSZ, wt2b + 0,  a0, seg, 2 * MSZ, 2 * D_);
    gemm_pass<true,  true ><<<gt, 256, 0, stream>>>(a0, wb + 13 * MSZ, wt2b + D_, a1, seg, 2 * MSZ, 2 * D_);
    // head: D->64 (+bias, no relu), dot h2, sigmoid, scatter
    head_pass<<<dim3(128), 256, 0, stream>>>(a1, wb + H1T_ELEM_OFF, h1b, h2W, h2b, seg, perm, (float*)d_out);
}